// Round 6
// baseline (198.197 us; speedup 1.0000x reference)
//
#include <hip/hip_runtime.h>

// CTC forward loss. T=1024, B=128, C=256, S=64, L=129.
// 5 waves per block (one block per batch element):
//   waves 1-4 (producers, R14): gather lp[t][b][tgt_lane] + lp[t][b][0],
//     exp() both, stage {eml, ebl} float2 into a 2-chunk LDS ring. Each
//     producer owns 16 rows/chunk and keeps TWO chunk-slices in flight
//     (groups G0={A,Bx}, G1={Cx,Dx}, chunk parity c&1): at iter kc it
//     drains chunk kc+1 (loads issued at kc-2) and issues chunk kc+3 into
//     the just-freed group. Rationale: per-wave outstanding VMEM is capped
//     (~63, 6-bit vmcnt), so R13's 2 waves x 64 loads was the per-wave
//     ceiling; 4 waves x (16 rows x 2 slices)=64/wave doubles the BLOCK's
//     in-flight loads to ~256 -> Little's-law parallelism toward the
//     ~20 us HBM floor for the 134 MB gather (R13 post-mortem: consumer
//     op-cuts were invisible => producer side is the exposed bound).
//   wave 0 (consumer): alpha recurrence in SCALED LINEAR FP32 with a
//     PER-LANE integer exponent: p_s = exp(alpha_s) * 2^es_lane. Cross-lane
//     term (pprev = pb[lane-1]) re-framed exactly by one v_ldexp_f32 with
//     des = es_prev - es. Per-lane rescale every 8 steps recenters the lane
//     max at 2^32. Lane i holds p[2i] ("pa"), p[2i+1] ("pb"); lane 63 also
//     p[128] ("pc"). ds_reads pipelined with rotating float2 regs (dist 4).
// R12: whole-lane-dead adoption fix (absmax 2.5 -> 0.0).
// R13a: des-HOISTED fast path for kc >= 2 (all lanes provably live after
//     t=128; es changes only at RESCALE) -> 9 VALU/step, bit-identical.
// R13b: reduce kernel FUSED via atomicAdd(out, loss/(tl*B)) — harness
//     zeroes out before the checked launch and between timed iterations.

#define NEGV (-1e30f)
#define NEGH (-5e29f)

constexpr int T_  = 1024;
constexpr int C_  = 256;
constexpr int CH  = 64;        // rows per chunk
constexpr int NCH = T_ / CH;   // 16 chunks covering t = 1 .. 1024

__device__ __forceinline__ float lse2f(float x, float y) {
    float m = fmaxf(x, y);
    float s = __expf(x - m) + __expf(y - m);
    float r = m + __logf(s);
    return (m > NEGH) ? r : NEGV;
}

// ---- producer register-set macros (named regs; R6: arrays are NOT promoted)
#define PDECL(S) float S##g0,S##g1,S##g2,S##g3,S##g4,S##g5,S##g6,S##g7, \
                       S##l0,S##l1,S##l2,S##l3,S##l4,S##l5,S##l6,S##l7
#define PLOAD1(S,J,TB) { int t_ = (TB) + J; t_ = t_ > 1023 ? 1023 : t_;      \
    const float* rp_ = rowb + (size_t)t_ * BC;                               \
    S##g##J = rp_[my_tgt]; S##l##J = rp_[0]; }
#define PLOAD(S,TB) PLOAD1(S,0,TB) PLOAD1(S,1,TB) PLOAD1(S,2,TB)             \
                    PLOAD1(S,3,TB) PLOAD1(S,4,TB) PLOAD1(S,5,TB)             \
                    PLOAD1(S,6,TB) PLOAD1(S,7,TB)
#define PSTORE1(S,J,RB,BUFP) BUFP[((RB) + J) * 64 + lane] =                  \
    make_float2(__expf(S##g##J), __expf(S##l##J));
#define PSTORE(S,RB,BUFP) PSTORE1(S,0,RB,BUFP) PSTORE1(S,1,RB,BUFP)          \
                          PSTORE1(S,2,RB,BUFP) PSTORE1(S,3,RB,BUFP)          \
                          PSTORE1(S,4,RB,BUFP) PSTORE1(S,5,RB,BUFP)          \
                          PSTORE1(S,6,RB,BUFP) PSTORE1(S,7,RB,BUFP)
// 16-row half-chunk group: 32 loads in flight per group, 2 groups/wave
#define LOADG(S1,S2,T0)      PLOAD(S1,(T0)) PLOAD(S2,(T0)+8)
#define STOREG(S1,S2,RB,BUFP) PSTORE(S1,(RB),BUFP) PSTORE(S2,(RB)+8,BUFP)

__global__ __launch_bounds__(320) void ctc_alpha_kernel(
    const float* __restrict__ lp,      // (T, B, C) log-probs
    const int* __restrict__ targets,   // (B*S,)
    const int* __restrict__ in_len,    // (B,)
    const int* __restrict__ tgt_len,   // (B,)
    float* __restrict__ out_loss,      // (1,) mean loss (atomic-accumulated)
    int B, int S)
{
    __shared__ float2 stage[2][CH * 64];   // 64 KiB emit-pair ring
    __shared__ float sh[132];

    const int b    = blockIdx.x;
    const int tid  = threadIdx.x;
    const int wave = tid >> 6;
    const int lane = tid & 63;
    const int BC   = B * C_;
    const float* rowb = lp + (size_t)b * C_;   // row at time t: rowb + t*BC

    int my_tgt = (lane < S) ? targets[b * S + lane] : 0;
    int prev_tgt = __shfl_up(my_tgt, 1);
    const bool skip = (lane > 0) && (my_tgt != prev_tgt) && (my_tgt != 0);
    const float skipf = skip ? 1.f : 0.f;
    const int ilen = in_len[b];

    // f32 linear-domain state: value = p * 2^es  (es PER LANE)
    float pa = 0.f, pb = 0.f, pc = 0.f;
    int es = 0;

    PDECL(A); PDECL(Bx); PDECL(Cx); PDECL(Dx);   // producer in-flight regs
    const int r0 = (wave - 1) * 16;              // producer row base (wave0: unused)

    if (wave >= 1) {
        // chunk 0 (G0): load + drain now. chunk 1 (G1) + chunk 2 (G0):
        // loads stay in flight across the barrier (2-deep pipeline).
        LOADG(A, Bx, 1 + r0);
        { float2* bp = &stage[0][0]; STOREG(A, Bx, r0, bp); }
        LOADG(Cx, Dx, 1 + CH + r0);        // chunk 1 -> G1
        LOADG(A,  Bx, 1 + 2 * CH + r0);    // chunk 2 -> G0
    } else if (lane == 0) {
        pa = __expf(rowb[0]);        // alpha0[0]
        pb = __expf(rowb[my_tgt]);   // alpha0[1]
    }
    __syncthreads();   // chunk 0 staged

    // Per-step-adoption STEP (chunks 0-1 + boundary): 2 DPP, whole-lane-dead
    // frame adoption, exact re-framing of pprev, 7-op f32 core. des clamped
    // at +64 as inf-insurance.
#define STEP(cur) {                                                          \
        float eml = (cur).x;                                                 \
        float ebl = (cur).y;                                                 \
        int praw = __builtin_amdgcn_update_dpp(0, __float_as_int(pb),        \
                                               0x138, 0xf, 0xf, false);      \
        int esp  = __builtin_amdgcn_update_dpp(0, es,                        \
                                               0x138, 0xf, 0xf, false);      \
        bool dead = (fmaxf(fmaxf(pa, pb), pc) == 0.f);                       \
        es = dead ? esp : es;          /* whole lane dead: adopt left frame*/\
        int des = min(esp - es, 64);                                         \
        float pprev = ldexpf(__int_as_float(praw), des);   /* p[2i-1] */     \
        float t0s = pa + pb;                                                 \
        float nb = fmaf(skipf, pprev, t0s) * eml;   /* state 2i+1 */         \
        float na = (pa + pprev) * ebl;       /* state 2i   */                \
        float nc = (pc + pb) * ebl;          /* state 128  */                \
        pa = na; pb = nb; pc = nc; }

    // Fast STEP (kc >= 2, all lanes live, es window-constant): des is a
    // window-hoisted constant -> 9 VALU/step, bit-identical to STEP.
#define FSTEP(cur, DES) {                                                    \
        float eml = (cur).x;                                                 \
        float ebl = (cur).y;                                                 \
        int praw = __builtin_amdgcn_update_dpp(0, __float_as_int(pb),        \
                                               0x138, 0xf, 0xf, false);      \
        float pprev = ldexpf(__int_as_float(praw), DES);   /* p[2i-1] */     \
        float t0s = pa + pb;                                                 \
        float nb = fmaf(skipf, pprev, t0s) * eml;   /* state 2i+1 */         \
        float na = (pa + pprev) * ebl;       /* state 2i   */                \
        float nc = (pc + pb) * ebl;          /* state 128  */                \
        pa = na; pb = nb; pc = nc; }

    // Per-lane rescale: recenter lane max at 2^32 (exact power-of-2 shift).
    // Dead lanes (max==0) keep es.
#define RESCALE() {                                                          \
        int hb = __float_as_int(fmaxf(fmaxf(pa, pb), pc));                   \
        int sh_ = hb ? (159 - (hb >> 23)) : 0;    /* 32 - E */               \
        pa = ldexpf(pa, sh_); pb = ldexpf(pb, sh_); pc = ldexpf(pc, sh_);    \
        es -= sh_; }

    for (int kc = 0; kc < NCH; ++kc) {
        if (wave >= 1) {
            // group parity: chunk c lives in group c&1; (kc+3)&1 == (kc+1)&1
            if (((kc + 1) & 1) == 0) {
                if (kc + 1 < NCH) {              // drain chunk kc+1 (G0)
                    float2* bp = &stage[(kc + 1) & 1][0];
                    STOREG(A, Bx, r0, bp);
                }
                if (kc + 3 < NCH) {              // issue chunk kc+3 (G0)
                    LOADG(A, Bx, 1 + (kc + 3) * CH + r0);
                }
            } else {
                if (kc + 1 < NCH) {              // drain chunk kc+1 (G1)
                    float2* bp = &stage[(kc + 1) & 1][0];
                    STOREG(Cx, Dx, r0, bp);
                }
                if (kc + 3 < NCH) {              // issue chunk kc+3 (G1)
                    LOADG(Cx, Dx, 1 + (kc + 3) * CH + r0);
                }
            }
        } else {
            const int t0 = 1 + kc * CH;
            const float2* sb = &stage[kc & 1][lane];   // row stride 64
            if (t0 + CH <= ilen) {
                float2 f0 = sb[0 * 64];
                float2 f1 = sb[1 * 64];
                float2 f2 = sb[2 * 64];
                float2 f3 = sb[3 * 64];
                if (kc >= 2) {
                    // fast path: live lanes, hoisted des per 8-step window
                    int des = 0;
#pragma unroll
                    for (int r = 0; r < CH; ++r) {
                        if ((r & 7) == 0) {
                            int esp = __builtin_amdgcn_update_dpp(
                                0, es, 0x138, 0xf, 0xf, false);
                            des = min(esp - es, 64);
                        }
                        float2 cur = f0;
                        f0 = f1; f1 = f2; f2 = f3;
                        if (r + 4 < CH) f3 = sb[(r + 4) * 64];
                        FSTEP(cur, des);
                        if ((r & 7) == 7) RESCALE();
                    }
                } else {
                    // chunks 0-1: dead lanes may exist -> per-step adoption
#pragma unroll
                    for (int r = 0; r < CH; ++r) {
                        float2 cur = f0;
                        f0 = f1; f1 = f2; f2 = f3;
                        if (r + 4 < CH) f3 = sb[(r + 4) * 64];
                        STEP(cur);
                        if ((r & 7) == 7) RESCALE();
                    }
                }
            } else if (t0 < ilen) {
                // boundary chunk: wave-uniform per-step mask, full STEP
                float2 f0 = sb[0 * 64];
                float2 f1 = sb[1 * 64];
                float2 f2 = sb[2 * 64];
                float2 f3 = sb[3 * 64];
#pragma unroll
                for (int r = 0; r < CH; ++r) {
                    float2 cur = f0;
                    f0 = f1; f1 = f2; f2 = f3;
                    if (r + 4 < CH) f3 = sb[(r + 4) * 64];
                    if (t0 + r < ilen) {
                        STEP(cur);
                        if ((r & 7) == 7) RESCALE();
                    }
                }
            }
        }
        __syncthreads();   // chunk boundary: stage drained, buffers swap
    }

    // Epilogue: p (f32) + per-lane es -> log-domain float, lane 0 -> loss,
    // fused mean via one atomicAdd per block (harness zeroes out first).
    if (wave == 0) {
        const double lses = (double)es * 0.6931471805599453;   // per-lane
        auto logp = [&](float p) -> float {
            if (p == 0.f) return NEGV;
            float q = p * 33554432.0f;          // *2^25: normalize denormals
            if (q == 0.f) return NEGV;          // (covers FTZ mode too)
            int h = __float_as_int(q);
            int E = ((h >> 23) & 0xff) - 127 - 25;
            float m = __int_as_float((h & 0x807fffff) | (127 << 23)); // [1,2)
            return (float)(__logf(m) + ((double)E * 0.6931471805599453 + lses));
        };
        sh[2 * lane]     = logp(pa);
        sh[2 * lane + 1] = logp(pb);
        if (lane == 63) sh[128] = logp(pc);
    }
    __syncthreads();
    if (tid == 0) {
        int tl = tgt_len[b];
        int hi2 = 2 * tl;
        float ll = lse2f(sh[hi2], sh[hi2 - 1]);
        float loss = (ll > NEGH) ? -ll : 0.f;
        atomicAdd(out_loss, loss / ((float)tl * (float)B));
    }
}

extern "C" void kernel_launch(void* const* d_in, const int* in_sizes, int n_in,
                              void* d_out, int out_size, void* d_ws, size_t ws_size,
                              hipStream_t stream)
{
    const float* lp      = (const float*)d_in[0];  // (T,B,C) float32
    const int*   targets = (const int*)d_in[1];    // (B*S,)  int32
    const int*   il      = (const int*)d_in[2];    // (B,)
    const int*   tl      = (const int*)d_in[3];    // (B,)
    const int B = in_sizes[2];
    const int S = in_sizes[1] / B;

    ctc_alpha_kernel<<<B, 320, 0, stream>>>(lp, targets, il, tl,
                                            (float*)d_out, B, S);
}

// Round 7
// 194.901 us; speedup vs baseline: 1.0169x; 1.0169x over previous
//
#include <hip/hip_runtime.h>

// CTC forward loss. T=1024, B=128, C=256, S=64, L=129.
// 3 waves per block (one block per batch element):
//   waves 1-2 (producers): gather lp[t][b][tgt_lane] + lp[t][b][0], exp()
//     both, stage {eml, ebl} float2 into a 2-chunk LDS ring, pipelined
//     ACROSS the chunk barrier (loads of chunk kc+2 issued while consumer
//     eats kc, drained into LDS during kc+1).
//   wave 0 (consumer): alpha recurrence in SCALED LINEAR FP32 with a
//     PER-LANE integer exponent: p_s = exp(alpha_s) * 2^es_lane. Cross-lane
//     term (pprev = pb[lane-1]) re-framed exactly by one v_ldexp_f32 with
//     des = es_prev - es. Per-lane rescale every 8 steps recenters the lane
//     max at 2^32. Lane i holds p[2i] ("pa"), p[2i+1] ("pb"); lane 63 also
//     p[128] ("pc"). ds_reads pipelined with rotating float2 regs (dist 4).
// R12: whole-lane-dead adoption fix (absmax 2.5 -> 0.0).
// R13a: des-HOISTED fast path for kc >= 2 (all lanes provably live after
//     t=128; es changes only at RESCALE) -> 9 VALU/step, bit-identical.
// R13b: reduce kernel FUSED via atomicAdd(out, loss/(tl*B)).
// R15: REVERT of R14 (4 producer waves, 2-deep/wave: 198.2 us, +2.9 vs
//     R13). R14 falsified the memory-parallelism theory — extra waves only
//     added barrier-arrival cost. R13 is the best verified config
//     (195.3 us, absmax 0.0); restoring it verbatim. Cross-round evidence
//     (R9-R14: six structures, 195.1-199.3 us) says the alpha kernel is at
//     its ~20 us gather-BW floor plus harness-fixed time (2x ~78 us
//     re-poison fills at 86% HBM peak dominate dur_us).

#define NEGV (-1e30f)
#define NEGH (-5e29f)

constexpr int T_  = 1024;
constexpr int C_  = 256;
constexpr int CH  = 64;        // rows per chunk
constexpr int NCH = T_ / CH;   // 16 chunks covering t = 1 .. 1024

__device__ __forceinline__ float lse2f(float x, float y) {
    float m = fmaxf(x, y);
    float s = __expf(x - m) + __expf(y - m);
    float r = m + __logf(s);
    return (m > NEGH) ? r : NEGV;
}

// ---- producer register-set macros (named regs; R6: arrays are NOT promoted)
#define PDECL(S) float S##g0,S##g1,S##g2,S##g3,S##g4,S##g5,S##g6,S##g7, \
                       S##l0,S##l1,S##l2,S##l3,S##l4,S##l5,S##l6,S##l7
#define PLOAD1(S,J,TB) { int t_ = (TB) + J; t_ = t_ > 1023 ? 1023 : t_;      \
    const float* rp_ = rowb + (size_t)t_ * BC;                               \
    S##g##J = rp_[my_tgt]; S##l##J = rp_[0]; }
#define PLOAD(S,TB) PLOAD1(S,0,TB) PLOAD1(S,1,TB) PLOAD1(S,2,TB)             \
                    PLOAD1(S,3,TB) PLOAD1(S,4,TB) PLOAD1(S,5,TB)             \
                    PLOAD1(S,6,TB) PLOAD1(S,7,TB)
#define PSTORE1(S,J,RB,BUFP) BUFP[((RB) + J) * 64 + lane] =                  \
    make_float2(__expf(S##g##J), __expf(S##l##J));
#define PSTORE(S,RB,BUFP) PSTORE1(S,0,RB,BUFP) PSTORE1(S,1,RB,BUFP)          \
                          PSTORE1(S,2,RB,BUFP) PSTORE1(S,3,RB,BUFP)          \
                          PSTORE1(S,4,RB,BUFP) PSTORE1(S,5,RB,BUFP)          \
                          PSTORE1(S,6,RB,BUFP) PSTORE1(S,7,RB,BUFP)
// whole 32-row chunk slice in registers: 64 floats/lane in flight
#define LOADCHUNK(T0) PLOAD(A,(T0)) PLOAD(Bx,(T0)+8)                         \
                      PLOAD(Cx,(T0)+16) PLOAD(Dx,(T0)+24)
#define STORECHUNK(RB,BUFP) PSTORE(A,(RB),BUFP) PSTORE(Bx,(RB)+8,BUFP)       \
                            PSTORE(Cx,(RB)+16,BUFP) PSTORE(Dx,(RB)+24,BUFP)

__global__ __launch_bounds__(192) void ctc_alpha_kernel(
    const float* __restrict__ lp,      // (T, B, C) log-probs
    const int* __restrict__ targets,   // (B*S,)
    const int* __restrict__ in_len,    // (B,)
    const int* __restrict__ tgt_len,   // (B,)
    float* __restrict__ out_loss,      // (1,) mean loss (atomic-accumulated)
    int B, int S)
{
    __shared__ float2 stage[2][CH * 64];   // 64 KiB emit-pair ring
    __shared__ float sh[132];

    const int b    = blockIdx.x;
    const int tid  = threadIdx.x;
    const int wave = tid >> 6;
    const int lane = tid & 63;
    const int BC   = B * C_;
    const float* rowb = lp + (size_t)b * C_;   // row at time t: rowb + t*BC

    int my_tgt = (lane < S) ? targets[b * S + lane] : 0;
    int prev_tgt = __shfl_up(my_tgt, 1);
    const bool skip = (lane > 0) && (my_tgt != prev_tgt) && (my_tgt != 0);
    const float skipf = skip ? 1.f : 0.f;
    const int ilen = in_len[b];

    // f32 linear-domain state: value = p * 2^es  (es PER LANE)
    float pa = 0.f, pb = 0.f, pc = 0.f;
    int es = 0;

    PDECL(A); PDECL(Bx); PDECL(Cx); PDECL(Dx);   // producer in-flight regs
    const int r0 = (wave - 1) * 32;              // producer row base (wave0: unused)

    if (wave >= 1) {
        // chunk 0: load + drain now; chunk 1: loads in flight across barrier
        LOADCHUNK(1 + r0);
        { float2* bp = &stage[0][0]; STORECHUNK(r0, bp); }
        LOADCHUNK(1 + CH + r0);
    } else if (lane == 0) {
        pa = __expf(rowb[0]);        // alpha0[0]
        pb = __expf(rowb[my_tgt]);   // alpha0[1]
    }
    __syncthreads();   // chunk 0 staged

    // Per-step-adoption STEP (chunks 0-1 + boundary): 2 DPP, whole-lane-dead
    // frame adoption, exact re-framing of pprev, 7-op f32 core. des clamped
    // at +64 as inf-insurance.
#define STEP(cur) {                                                          \
        float eml = (cur).x;                                                 \
        float ebl = (cur).y;                                                 \
        int praw = __builtin_amdgcn_update_dpp(0, __float_as_int(pb),        \
                                               0x138, 0xf, 0xf, false);      \
        int esp  = __builtin_amdgcn_update_dpp(0, es,                        \
                                               0x138, 0xf, 0xf, false);      \
        bool dead = (fmaxf(fmaxf(pa, pb), pc) == 0.f);                       \
        es = dead ? esp : es;          /* whole lane dead: adopt left frame*/\
        int des = min(esp - es, 64);                                         \
        float pprev = ldexpf(__int_as_float(praw), des);   /* p[2i-1] */     \
        float t0s = pa + pb;                                                 \
        float nb = fmaf(skipf, pprev, t0s) * eml;   /* state 2i+1 */         \
        float na = (pa + pprev) * ebl;       /* state 2i   */                \
        float nc = (pc + pb) * ebl;          /* state 128  */                \
        pa = na; pb = nb; pc = nc; }

    // Fast STEP (kc >= 2, all lanes live, es window-constant): des is a
    // window-hoisted constant -> 9 VALU/step, bit-identical to STEP.
#define FSTEP(cur, DES) {                                                    \
        float eml = (cur).x;                                                 \
        float ebl = (cur).y;                                                 \
        int praw = __builtin_amdgcn_update_dpp(0, __float_as_int(pb),        \
                                               0x138, 0xf, 0xf, false);      \
        float pprev = ldexpf(__int_as_float(praw), DES);   /* p[2i-1] */     \
        float t0s = pa + pb;                                                 \
        float nb = fmaf(skipf, pprev, t0s) * eml;   /* state 2i+1 */         \
        float na = (pa + pprev) * ebl;       /* state 2i   */                \
        float nc = (pc + pb) * ebl;          /* state 128  */                \
        pa = na; pb = nb; pc = nc; }

    // Per-lane rescale: recenter lane max at 2^32 (exact power-of-2 shift).
    // Dead lanes (max==0) keep es.
#define RESCALE() {                                                          \
        int hb = __float_as_int(fmaxf(fmaxf(pa, pb), pc));                   \
        int sh_ = hb ? (159 - (hb >> 23)) : 0;    /* 32 - E */               \
        pa = ldexpf(pa, sh_); pb = ldexpf(pb, sh_); pc = ldexpf(pc, sh_);    \
        es -= sh_; }

    for (int kc = 0; kc < NCH; ++kc) {
        if (wave >= 1) {
            if (kc + 1 < NCH) {     // drain loads issued one chunk ago
                float2* bp = &stage[(kc + 1) & 1][0];
                STORECHUNK(r0, bp);
            }
            if (kc + 2 < NCH) {     // issue next chunk's loads; full window
                LOADCHUNK(1 + (kc + 2) * CH + r0);   // to complete before use
            }
        } else {
            const int t0 = 1 + kc * CH;
            const float2* sb = &stage[kc & 1][lane];   // row stride 64
            if (t0 + CH <= ilen) {
                float2 f0 = sb[0 * 64];
                float2 f1 = sb[1 * 64];
                float2 f2 = sb[2 * 64];
                float2 f3 = sb[3 * 64];
                if (kc >= 2) {
                    // fast path: live lanes, hoisted des per 8-step window
                    int des = 0;
#pragma unroll
                    for (int r = 0; r < CH; ++r) {
                        if ((r & 7) == 0) {
                            int esp = __builtin_amdgcn_update_dpp(
                                0, es, 0x138, 0xf, 0xf, false);
                            des = min(esp - es, 64);
                        }
                        float2 cur = f0;
                        f0 = f1; f1 = f2; f2 = f3;
                        if (r + 4 < CH) f3 = sb[(r + 4) * 64];
                        FSTEP(cur, des);
                        if ((r & 7) == 7) RESCALE();
                    }
                } else {
                    // chunks 0-1: dead lanes may exist -> per-step adoption
#pragma unroll
                    for (int r = 0; r < CH; ++r) {
                        float2 cur = f0;
                        f0 = f1; f1 = f2; f2 = f3;
                        if (r + 4 < CH) f3 = sb[(r + 4) * 64];
                        STEP(cur);
                        if ((r & 7) == 7) RESCALE();
                    }
                }
            } else if (t0 < ilen) {
                // boundary chunk: wave-uniform per-step mask, full STEP
                float2 f0 = sb[0 * 64];
                float2 f1 = sb[1 * 64];
                float2 f2 = sb[2 * 64];
                float2 f3 = sb[3 * 64];
#pragma unroll
                for (int r = 0; r < CH; ++r) {
                    float2 cur = f0;
                    f0 = f1; f1 = f2; f2 = f3;
                    if (r + 4 < CH) f3 = sb[(r + 4) * 64];
                    if (t0 + r < ilen) {
                        STEP(cur);
                        if ((r & 7) == 7) RESCALE();
                    }
                }
            }
        }
        __syncthreads();   // chunk boundary: stage drained, buffers swap
    }

    // Epilogue: p (f32) + per-lane es -> log-domain float, lane 0 -> loss,
    // fused mean via one atomicAdd per block (harness zeroes out first).
    if (wave == 0) {
        const double lses = (double)es * 0.6931471805599453;   // per-lane
        auto logp = [&](float p) -> float {
            if (p == 0.f) return NEGV;
            float q = p * 33554432.0f;          // *2^25: normalize denormals
            if (q == 0.f) return NEGV;          // (covers FTZ mode too)
            int h = __float_as_int(q);
            int E = ((h >> 23) & 0xff) - 127 - 25;
            float m = __int_as_float((h & 0x807fffff) | (127 << 23)); // [1,2)
            return (float)(__logf(m) + ((double)E * 0.6931471805599453 + lses));
        };
        sh[2 * lane]     = logp(pa);
        sh[2 * lane + 1] = logp(pb);
        if (lane == 63) sh[128] = logp(pc);
    }
    __syncthreads();
    if (tid == 0) {
        int tl = tgt_len[b];
        int hi2 = 2 * tl;
        float ll = lse2f(sh[hi2], sh[hi2 - 1]);
        float loss = (ll > NEGH) ? -ll : 0.f;
        atomicAdd(out_loss, loss / ((float)tl * (float)B));
    }
}

extern "C" void kernel_launch(void* const* d_in, const int* in_sizes, int n_in,
                              void* d_out, int out_size, void* d_ws, size_t ws_size,
                              hipStream_t stream)
{
    const float* lp      = (const float*)d_in[0];  // (T,B,C) float32
    const int*   targets = (const int*)d_in[1];    // (B*S,)  int32
    const int*   il      = (const int*)d_in[2];    // (B,)
    const int*   tl      = (const int*)d_in[3];    // (B,)
    const int B = in_sizes[2];
    const int S = in_sizes[1] / B;

    ctc_alpha_kernel<<<B, 192, 0, stream>>>(lp, targets, il, tl,
                                            (float*)d_out, B, S);
}